// Round 7
// baseline (615.431 us; speedup 1.0000x reference)
//
#include <hip/hip_runtime.h>
#include <math.h>
#include <stdint.h>

typedef _Float16 f16;
typedef f16 f16x8 __attribute__((ext_vector_type(8)));
typedef f16 f16x4 __attribute__((ext_vector_type(4)));
typedef float f32x4 __attribute__((ext_vector_type(4)));

#define N_ITERS 7
#define HF 10      // GRU hidden size
#define NIN 9      // node inputs
#define EF 11      // edge features / message size
#define GIN (EF + NIN)

#define S1 40      // f16 row stride for W1 (K=32 padded)
#define S2 104     // f16 row stride for W2/W3/W4
#define G  2       // 16-edge groups per wave
#define MSTR 12    // msg row stride in f16 (11 + 1 pad, 24B)

union FragU { f16x8 v; uint32_t u[4]; int d[4]; uint2 p2[2]; uint4 q4; };

// ---------------- weight preconversion (once per launch) ----------------
__global__ __launch_bounds__(256) void convert_weights(
    const float* __restrict__ W1, const float* __restrict__ W2,
    const float* __restrict__ W3, const float* __restrict__ W4,
    f16* __restrict__ wf)
{
    f16* wf1 = wf;
    f16* wf2 = wf1 + 96 * S1;
    f16* wf3 = wf2 + 96 * S2;
    f16* wf4 = wf3 + 96 * S2;
    const int tid = blockIdx.x * 256 + threadIdx.x;
    const int nt = gridDim.x * 256;
    for (int i = tid; i < 96 * S1; i += nt) {
        int m = i / S1, k = i % S1;
        wf1[i] = (k < 31) ? (f16)W1[m * 31 + k] : (f16)0.f;
    }
    for (int i = tid; i < 96 * S2; i += nt) {
        int m = i / S2, k = i % S2;
        wf2[i] = (k < 96) ? (f16)W2[m * 96 + k] : (f16)0.f;
        wf3[i] = (k < 96) ? (f16)W3[m * 96 + k] : (f16)0.f;
    }
    for (int i = tid; i < 16 * S2; i += nt) {
        int m = i / S2, k = i % S2;
        wf4[i] = (m < 11 && k < 96) ? (f16)W4[m * 96 + k] : (f16)0.f;
    }
}

// ---------------- CSR construction (dst_ids is launch-invariant) ----------
__global__ __launch_bounds__(256) void count_edges(
    const int* __restrict__ dst, int* __restrict__ cnt, int E)
{
    int e = blockIdx.x * 256 + threadIdx.x;
    if (e < E) atomicAdd(&cnt[dst[e]], 1);
}

// single-block exclusive scan over cnt[0..N) -> row_ptr[0..N], nxt = copy
__global__ __launch_bounds__(1024) void scan_counts(
    const int* __restrict__ cnt, int* __restrict__ row_ptr,
    int* __restrict__ nxt, int N, int E)
{
    __shared__ int sums[1024];
    const int tid = threadIdx.x;
    const int C = (N + 1023) >> 10;
    const int base = tid * C;
    int local = 0;
    for (int i = 0; i < C; ++i) {
        int idx = base + i;
        if (idx < N) local += cnt[idx];
    }
    sums[tid] = local;
    __syncthreads();
    for (int off = 1; off < 1024; off <<= 1) {
        int v = (tid >= off) ? sums[tid - off] : 0;
        __syncthreads();
        sums[tid] += v;
        __syncthreads();
    }
    int run = sums[tid] - local;   // exclusive prefix of this chunk
    for (int i = 0; i < C; ++i) {
        int idx = base + i;
        if (idx < N) {
            row_ptr[idx] = run;
            nxt[idx] = run;
            run += cnt[idx];
        }
    }
    if (tid == 0) row_ptr[N] = E;
}

// fused scatter + edge-attr f16 packing directly into dst-sorted slots
__global__ __launch_bounds__(256) void scatter_pack(
    const int* __restrict__ src, const int* __restrict__ dst,
    const float* __restrict__ ea, int* __restrict__ nxt,
    int* __restrict__ srcs, int* __restrict__ dsts,
    f16* __restrict__ eaA, f16* __restrict__ eaB, int E)
{
    int e = blockIdx.x * 256 + threadIdx.x;
    if (e >= E) return;
    const int d = dst[e];
    const int pos = atomicAdd(&nxt[d], 1);
    srcs[pos] = src[e];
    dsts[pos] = d;
    const float* r = ea + (size_t)e * EF;
    f16x4 a;
#pragma unroll
    for (int j = 0; j < 4; ++j) a[j] = (f16)r[j];
    *(f16x4*)(eaA + (size_t)pos * 4) = a;
    f16x8 b;
#pragma unroll
    for (int j = 0; j < 7; ++j) b[j] = (f16)r[4 + j];
    b[7] = (f16)0.f;
    *(f16x8*)(eaB + (size_t)pos * 8) = b;
}

// relu pair -> packed dword of 2 f16
__device__ __forceinline__ uint32_t pack_relu2(float x, float y) {
    union { f16 h[2]; uint32_t u; } p;
    p.h[0] = (f16)fmaxf(x, 0.0f);
    p.h[1] = (f16)fmaxf(y, 0.0f);
    return p.u;
}

// C/D-layout -> B-operand-layout lane permutation (register-only, no LDS).
//
// dest lane (n,q), B dword dw of kb needs:
//   value half : pf0 if dw even (C regs 0,1), pf1 if dw odd (C regs 2,3)
//   t-block    : t = 2*kb + (q_dest >> 1)
//   source lane: n + 32*(q_dest & 1) + 16*(dw >> 1)
// ds_bpermute is a PULL: each lane CONTRIBUTES one value; a single bpermute
// cannot serve the two dest lanes (q>>1 = 0 and 1) that pull different
// t-blocks from the same source. (Round 6 bug: selecting t by the
// contributor's own lane id sent t=2kb+(q&1) — wrong for q=1,2.)
// Fix: contribute BOTH t-blocks (2 bpermutes) and v_cndmask on q>>1.
__device__ __forceinline__ void assemble_B(
    f16x8 bf[G][3], const uint32_t pf0[G][6], const uint32_t pf1[G][6],
    int srcA, int srcB, bool hi)
{
#pragma unroll
    for (int g = 0; g < G; ++g)
#pragma unroll
        for (int kb = 0; kb < 3; ++kb) {
            const int v0lo = (int)pf0[g][2 * kb], v0hi = (int)pf0[g][2 * kb + 1];
            const int v1lo = (int)pf1[g][2 * kb], v1hi = (int)pf1[g][2 * kb + 1];
            FragU u;
            {
                int lo = __builtin_amdgcn_ds_bpermute(srcA, v0lo);
                int hh = __builtin_amdgcn_ds_bpermute(srcA, v0hi);
                u.d[0] = hi ? hh : lo;
            }
            {
                int lo = __builtin_amdgcn_ds_bpermute(srcA, v1lo);
                int hh = __builtin_amdgcn_ds_bpermute(srcA, v1hi);
                u.d[1] = hi ? hh : lo;
            }
            {
                int lo = __builtin_amdgcn_ds_bpermute(srcB, v0lo);
                int hh = __builtin_amdgcn_ds_bpermute(srcB, v0hi);
                u.d[2] = hi ? hh : lo;
            }
            {
                int lo = __builtin_amdgcn_ds_bpermute(srcB, v1lo);
                int hh = __builtin_amdgcn_ds_bpermute(srcB, v1hi);
                u.d[3] = hi ? hh : lo;
            }
            bf[g][kb] = u.v;
        }
}

// ---------------- edge MLP via MFMA: zero LDS, register-resident ----------
__global__ __launch_bounds__(256, 4) void edge_mlp_mfma(
    const f16* __restrict__ h16, const f16* __restrict__ wf,
    const float* __restrict__ b1, const float* __restrict__ b2,
    const float* __restrict__ b3, const float* __restrict__ b4,
    const int* __restrict__ srcs, const int* __restrict__ dsts,
    const f16* __restrict__ eaA, const f16* __restrict__ eaB,
    f16* __restrict__ msg, int E)
{
    const f16* wf1 = wf;
    const f16* wf2 = wf1 + 96 * S1;
    const f16* wf3 = wf2 + 96 * S2;
    const f16* wf4 = wf3 + 96 * S2;

    const int wave = threadIdx.x >> 6;
    const int lane = threadIdx.x & 63;
    const int n = lane & 15;       // edge-in-group (B col / C col)
    const int q = lane >> 4;       // quad

    const int i0 = blockIdx.x * (4 * G * 16) + wave * (G * 16);

    // bpermute source-lane byte addresses for the C->B permutation
    const int srcA = (n + 32 * (q & 1)) << 2;
    const int srcB = srcA + (16 << 2);
    const bool hi = (q >= 2);

    const uint4* h16q = (const uint4*)h16;        // node = 2 uint4 (32B)
    const uint32_t* h16u = (const uint32_t*)h16;  // node = 8 dwords
    const uint2* eaAp = (const uint2*)eaA;
    const uint4* eaBp = (const uint4*)eaB;

    // ---------------- layer-1 input gather (quad-sliced) ----------------
    f16x8 bin[G];
#pragma unroll
    for (int g = 0; g < G; ++g) {
        const int ig = i0 + g * 16 + n;
        const int ii = (ig < E) ? ig : 0;
        FragU bfu;
        if (q == 0) {
            const int s = srcs[ii];
            bfu.q4 = h16q[(size_t)s * 2];                 // h_s[0..7]
        } else if (q == 1) {
            const int s = srcs[ii];
            const int d = dsts[ii];
            bfu.u[0] = h16u[(size_t)s * 8 + 4];           // h_s[8,9]
            uint2 t2 = *(const uint2*)(h16u + (size_t)d * 8);
            bfu.u[1] = t2.x; bfu.u[2] = t2.y;             // h_d[0..3]
            bfu.u[3] = h16u[(size_t)d * 8 + 2];           // h_d[4,5]
        } else if (q == 2) {
            const int d = dsts[ii];
            bfu.u[0] = h16u[(size_t)d * 8 + 3];           // h_d[6,7]
            bfu.u[1] = h16u[(size_t)d * 8 + 4];           // h_d[8,9]
            uint2 t2 = eaAp[ii];
            bfu.u[2] = t2.x; bfu.u[3] = t2.y;             // ea[0..3]
        } else {
            bfu.q4 = eaBp[ii];                            // ea[4..10],0
        }
        bin[g] = bfu.v;
    }

    uint32_t pf0[G][6], pf1[G][6];   // packed relu'd C halves per t-block
    f16x8 bf[G][3];                  // B-operand frags for the next layer

    // ---------------- layer 1: [31] -> [96] ----------------
#pragma unroll
    for (int t = 0; t < 6; ++t) {
        const f16x8 a = *(const f16x8*)(wf1 + (t * 16 + n) * S1 + 8 * q);
        const f32x4 bias = *(const f32x4*)(b1 + t * 16 + 4 * q);
#pragma unroll
        for (int g = 0; g < G; ++g) {
            f32x4 c = __builtin_amdgcn_mfma_f32_16x16x32_f16(a, bin[g], bias, 0, 0, 0);
            pf0[g][t] = pack_relu2(c[0], c[1]);
            pf1[g][t] = pack_relu2(c[2], c[3]);
        }
    }
    assemble_B(bf, pf0, pf1, srcA, srcB, hi);

    // ---------------- layers 2,3: [96] -> [96] ----------------
#pragma unroll 1
    for (int L = 0; L < 2; ++L) {
        const f16* w = L ? wf3 : wf2;
        const float* bb = L ? b3 : b2;
#pragma unroll
        for (int t = 0; t < 6; ++t) {
            const f16* wrow = w + (t * 16 + n) * S2 + 8 * q;
            const f16x8 a0 = *(const f16x8*)(wrow);
            const f16x8 a1 = *(const f16x8*)(wrow + 32);
            const f16x8 a2 = *(const f16x8*)(wrow + 64);
            const f32x4 bias = *(const f32x4*)(bb + t * 16 + 4 * q);
#pragma unroll
            for (int g = 0; g < G; ++g) {
                f32x4 c = __builtin_amdgcn_mfma_f32_16x16x32_f16(a0, bf[g][0], bias, 0, 0, 0);
                c = __builtin_amdgcn_mfma_f32_16x16x32_f16(a1, bf[g][1], c, 0, 0, 0);
                c = __builtin_amdgcn_mfma_f32_16x16x32_f16(a2, bf[g][2], c, 0, 0, 0);
                pf0[g][t] = pack_relu2(c[0], c[1]);
                pf1[g][t] = pack_relu2(c[2], c[3]);
            }
        }
        assemble_B(bf, pf0, pf1, srcA, srcB, hi);
    }

    // ---------------- layer 4: [96] -> [11(+pad)], f16 msg write ----------
    {
        const f16* wrow = wf4 + n * S2 + 8 * q;
        const f16x8 a0 = *(const f16x8*)(wrow);
        const f16x8 a1 = *(const f16x8*)(wrow + 32);
        const f16x8 a2 = *(const f16x8*)(wrow + 64);
        f32x4 biasv;
#pragma unroll
        for (int r = 0; r < 4; ++r) {
            const int m = 4 * q + r;
            biasv[r] = (m < 11) ? b4[m] : 0.0f;
        }
#pragma unroll
        for (int g = 0; g < G; ++g) {
            f32x4 c = __builtin_amdgcn_mfma_f32_16x16x32_f16(a0, bf[g][0], biasv, 0, 0, 0);
            c = __builtin_amdgcn_mfma_f32_16x16x32_f16(a1, bf[g][1], c, 0, 0, 0);
            c = __builtin_amdgcn_mfma_f32_16x16x32_f16(a2, bf[g][2], c, 0, 0, 0);
            const int ig = i0 + g * 16 + n;
            if (q < 3 && ig < E) {   // rows m=0..11; m=11 exact 0 (zero-padded W4/b4)
                f16x4 o;
#pragma unroll
                for (int r = 0; r < 4; ++r) o[r] = (f16)c[r];
                *(f16x4*)(msg + (size_t)ig * MSTR + 4 * q) = o;  // 8B store, 24B rows
            }
        }
    }
}

// ---------------- GRU + CSR aggregation + logits per node ----------------
__global__ __launch_bounds__(256) void gru_node_kernel(
    const float* __restrict__ node_inputs,
    float* __restrict__ h, f16* __restrict__ h16,
    const int* __restrict__ row_ptr, const f16* __restrict__ msg,
    const float* __restrict__ wih, const float* __restrict__ whh,
    const float* __restrict__ bih, const float* __restrict__ bhh,
    const float* __restrict__ fw, const float* __restrict__ fb,
    float* __restrict__ out_t, int N)
{
    const int n = blockIdx.x * blockDim.x + threadIdx.x;
    if (n >= N) return;

    float x[GIN];
#pragma unroll
    for (int k = 0; k < EF; ++k) x[k] = 0.0f;
    const int r0 = row_ptr[n], r1 = row_ptr[n + 1];
    for (int r = r0; r < r1; ++r) {
        const f16x4* mp = (const f16x4*)(msg + (size_t)r * MSTR);
        f16x4 a = mp[0], b = mp[1], c = mp[2];
#pragma unroll
        for (int j = 0; j < 4; ++j) x[j]     += (float)a[j];
#pragma unroll
        for (int j = 0; j < 4; ++j) x[4 + j] += (float)b[j];
#pragma unroll
        for (int j = 0; j < 3; ++j) x[8 + j] += (float)c[j];
    }
#pragma unroll
    for (int k = 0; k < NIN; ++k) x[EF + k] = node_inputs[(size_t)n * NIN + k];

    float hv[HF];
#pragma unroll
    for (int k = 0; k < HF; ++k) hv[k] = h[(size_t)n * HF + k];

    float gi[3 * HF];
    float gh[3 * HF];
#pragma unroll
    for (int j = 0; j < 3 * HF; ++j) {
        float a = bih[j];
#pragma unroll
        for (int k = 0; k < GIN; ++k) a = fmaf(x[k], wih[j * GIN + k], a);
        gi[j] = a;
        float g = bhh[j];
#pragma unroll
        for (int k = 0; k < HF; ++k) g = fmaf(hv[k], whh[j * HF + k], g);
        gh[j] = g;
    }

    float hn[HF];
#pragma unroll
    for (int k = 0; k < HF; ++k) {
        const float r = 1.0f / (1.0f + __expf(-(gi[k] + gh[k])));
        const float z = 1.0f / (1.0f + __expf(-(gi[HF + k] + gh[HF + k])));
        const float nn = tanhf(gi[2 * HF + k] + r * gh[2 * HF + k]);
        hn[k] = (1.0f - z) * nn + z * hv[k];
    }
#pragma unroll
    for (int k = 0; k < HF; ++k) {
        h[(size_t)n * HF + k] = hn[k];
        h16[(size_t)n * 16 + k] = (f16)hn[k];
    }

    float l0 = fb[0], l1 = fb[1];
#pragma unroll
    for (int k = 0; k < HF; ++k) {
        l0 = fmaf(hn[k], fw[k], l0);
        l1 = fmaf(hn[k], fw[HF + k], l1);
    }
    out_t[(size_t)n * 2 + 0] = l0;
    out_t[(size_t)n * 2 + 1] = l1;
}

extern "C" void kernel_launch(void* const* d_in, const int* in_sizes, int n_in,
                              void* d_out, int out_size, void* d_ws, size_t ws_size,
                              hipStream_t stream) {
    const float* node_inputs = (const float*)d_in[0];
    const float* edge_attr   = (const float*)d_in[1];
    const float* W1 = (const float*)d_in[2];
    const float* b1 = (const float*)d_in[3];
    const float* W2 = (const float*)d_in[4];
    const float* b2 = (const float*)d_in[5];
    const float* W3 = (const float*)d_in[6];
    const float* b3 = (const float*)d_in[7];
    const float* W4 = (const float*)d_in[8];
    const float* b4 = (const float*)d_in[9];
    const float* gru_wih = (const float*)d_in[10];
    const float* gru_whh = (const float*)d_in[11];
    const float* gru_bih = (const float*)d_in[12];
    const float* gru_bhh = (const float*)d_in[13];
    const float* fin_w   = (const float*)d_in[14];
    const float* fin_b   = (const float*)d_in[15];
    const int* src_ids = (const int*)d_in[16];
    const int* dst_ids = (const int*)d_in[17];

    const int N = in_sizes[0] / NIN;   // 20000
    const int E = in_sizes[1] / EF;    // 320000

    // ---- workspace carve-up (256B-aligned chunks) ----
    // h16 / hbuf / cnt are adjacent so ONE memset zeroes all three.
    char* base = (char*)d_ws;
    size_t off = 0;
    auto alloc = [&](size_t bytes) -> char* {
        char* p = base + off;
        off += (bytes + 255) & ~(size_t)255;
        return p;
    };
    f16*   msg    = (f16*)  alloc((size_t)E * MSTR * 2);  // 7.7 MB
    f16*   eaB    = (f16*)  alloc((size_t)E * 8 * 2);
    f16*   eaA    = (f16*)  alloc((size_t)E * 4 * 2);
    f16*   h16    = (f16*)  alloc((size_t)N * 16 * 2);    // 640,000 B (256-mult)
    float* hbuf   = (float*)alloc((size_t)N * HF * 4);    // 800,000 B (256-mult)
    int*   cnt    = (int*)  alloc((size_t)N * 4);
    f16*   wf     = (f16*)  alloc(52000 * 2);
    int*   row_ptr= (int*)  alloc((size_t)(N + 1) * 4);
    int*   nxt    = (int*)  alloc((size_t)N * 4);
    int*   srcs   = (int*)  alloc((size_t)E * 4);
    int*   dsts   = (int*)  alloc((size_t)E * 4);

    const int eb_setup = (E + 255) / 256;
    const int eb = (E + 4 * G * 16 - 1) / (4 * G * 16);  // 128 edges per block
    const int nb = (N + 255) / 256;

    // ---- per-launch setup (d_ws is re-poisoned before every call) ----
    hipMemsetAsync(h16, 0, (size_t)N * 16 * 2 + (size_t)N * HF * 4 + (size_t)N * 4, stream);
    convert_weights<<<60, 256, 0, stream>>>(W1, W2, W3, W4, wf);
    count_edges<<<eb_setup, 256, 0, stream>>>(dst_ids, cnt, E);
    scan_counts<<<1, 1024, 0, stream>>>(cnt, row_ptr, nxt, N, E);
    scatter_pack<<<eb_setup, 256, 0, stream>>>(src_ids, dst_ids, edge_attr,
                                               nxt, srcs, dsts, eaA, eaB, E);

    float* out = (float*)d_out;
    for (int t = 0; t < N_ITERS; ++t) {
        edge_mlp_mfma<<<eb, 256, 0, stream>>>(
            h16, wf, b1, b2, b3, b4, srcs, dsts, eaA, eaB, msg, E);
        gru_node_kernel<<<nb, 256, 0, stream>>>(
            node_inputs, hbuf, h16, row_ptr, msg,
            gru_wih, gru_whh, gru_bih, gru_bhh,
            fin_w, fin_b, out + (size_t)t * N * 2, N);
    }
}